// Round 11
// baseline (387.707 us; speedup 1.0000x reference)
//
#include <hip/hip_runtime.h>
#include <hip/hip_bf16.h>

typedef float f32x4 __attribute__((ext_vector_type(4)));
typedef __bf16 bf16x8 __attribute__((ext_vector_type(8)));
typedef unsigned short u16x4 __attribute__((ext_vector_type(4)));

__device__ __forceinline__ unsigned short f2bf(float f) {
  unsigned u = __builtin_bit_cast(unsigned, f);
  u += 0x7FFFu + ((u >> 16) & 1u);
  return (unsigned short)(u >> 16);
}
__device__ __forceinline__ float bf2f(unsigned short h) {
  unsigned u = ((unsigned)h) << 16;
  return __builtin_bit_cast(float, u);
}

__device__ __forceinline__ void gload_lds16(const void* g, void* l) {
  __builtin_amdgcn_global_load_lds(
      (const __attribute__((address_space(1))) void*)g,
      (__attribute__((address_space(3))) void*)l, 16, 0, 0);
}

// ---------------- 128x128 BK=64 bf16 GEMM, 2 blocks/CU -----------------------
// C[m][n] = scale * sum_k A[m][k]*B[n][k] (+ bias[n]). A:[M][K], B:[N][K] bf16.
// Round-11 structural fix: previous 256^2 kernel used 128 KiB LDS -> only ONE
// block/CU -> block-wide barriers serialized LDS-reads, MFMA, and DMA waits
// (the invariant ~100us across rounds 6-10). This kernel: 64 KiB LDS (dbuf),
// 256 thr / 4 waves -> TWO blocks/CU; one block's MFMA phase overlaps the
// other's read/stage phase. r8's verified conflict-free swizzle + 16-row
// fragment reads (16x16x32 MFMA; 32-row reads of r10 measurably conflict).
// Per tile: {stage t+1 -> buf d^1 (8 gloads); read frags of d (16 ds_b128);
// 32 MFMA; vmcnt(0) [= only t+1's loads]; barrier}. No mid-tile barrier:
// stages never target the buffer being read.
#define BAR() __builtin_amdgcn_s_barrier()
#define VMW(N) asm volatile("s_waitcnt vmcnt(" #N ")" ::: "memory")
#define PRIO(x) __builtin_amdgcn_s_setprio(x)

#define MM16(a_, b_, c_)                                                      \
  c_ = __builtin_amdgcn_mfma_f32_16x16x32_bf16(                               \
      __builtin_bit_cast(bf16x8, a_), __builtin_bit_cast(bf16x8, b_), c_, 0, 0, 0)

template <int OUT_MODE, bool HAS_BIAS>
__global__ __launch_bounds__(256, 2) void gemm128(
    const unsigned short* __restrict__ A, const unsigned short* __restrict__ B,
    const float* __restrict__ bias, float scale, void* __restrict__ Cv,
    int N, int K, long sA, long sB, long sC, int gx, int gy) {
  __shared__ char sm[65536];  // A: [0,32K) = dbuf*16K; B: [32K,64K) same

  const int nwg = gridDim.x;
  int id = blockIdx.x;
  id = (id & 7) * (nwg >> 3) + (id >> 3);  // XCD swizzle (nwg % 8 == 0)
  const int bx = id % gx;
  const int by = (id / gx) % gy;
  const int bz = id / (gx * gy);

  const int t = threadIdx.x;
  const int lane = t & 63;
  const int w = t >> 6;   // 0..3
  const int wm = w >> 1;  // 0..1
  const int wn = w & 1;   // 0..1

  const int rowBase = by * 128;
  const int colBase = bx * 128;
  const unsigned short* Ab = A + sA * bz;
  const unsigned short* Bb = B + sB * bz;
  const int NT = K >> 6;  // K-tiles of 64

  // staging: tile = 128 rows x 64 cols = 16 KB; wave w issue j (0..3) covers
  // rows [w*32+j*8, +8); lane l -> row +(l>>3), slot l&7; src chunk inv-swz.
  const int srl = lane >> 3;
  const int schunk = (lane & 7) ^ srl;

#define STAGE(tt, d)                                                          \
  do {                                                                        \
    int _kt = (tt); if (_kt > NT - 1) _kt = NT - 1;                           \
    const int _k0 = _kt << 6;                                                 \
    _Pragma("unroll") for (int _j = 0; _j < 4; ++_j) {                        \
      const int _r = w * 32 + _j * 8 + srl;                                   \
      gload_lds16(Ab + (size_t)(rowBase + _r) * K + _k0 + schunk * 8,         \
                  sm + (d) * 16384 + (w * 4 + _j) * 1024);                    \
      gload_lds16(Bb + (size_t)(colBase + _r) * K + _k0 + schunk * 8,         \
                  sm + 32768 + (d) * 16384 + (w * 4 + _j) * 1024);            \
    }                                                                         \
  } while (0)

  // fragment reads (r8-verified conflict-free): row = base + f*16 + lr,
  // byte = row*128 + ((chunk ^ (row&7))<<4), chunk = kk*4 + g0; row&7==lr&7.
  const int lr = lane & 15;
  const int g0 = lane >> 4;
  const int sw0 = (g0 ^ (lr & 7)) << 4;
  const int sw1 = ((g0 + 4) ^ (lr & 7)) << 4;
  const int aBase = wm * 8192 + lr * 128;
  const int bBase = 32768 + wn * 8192 + lr * 128;

  uint4 Ar[4][2], Br[4][2];
  f32x4 acc[4][4];
#pragma unroll
  for (int m = 0; m < 4; ++m)
#pragma unroll
    for (int n = 0; n < 4; ++n) acc[m][n] = (f32x4){0.f, 0.f, 0.f, 0.f};

#define READ_FRAGS(d)                                                         \
  do {                                                                        \
    _Pragma("unroll") for (int f = 0; f < 4; ++f) {                           \
      Br[f][0] = *(const uint4*)(sm + (d) * 16384 + bBase + f * 2048 + sw0);  \
      Br[f][1] = *(const uint4*)(sm + (d) * 16384 + bBase + f * 2048 + sw1);  \
      Ar[f][0] = *(const uint4*)(sm + (d) * 16384 + aBase + f * 2048 + sw0);  \
      Ar[f][1] = *(const uint4*)(sm + (d) * 16384 + aBase + f * 2048 + sw1);  \
    }                                                                         \
  } while (0)

#define MFMA_ALL()                                                            \
  do {                                                                        \
    _Pragma("unroll") for (int kk = 0; kk < 2; ++kk)                          \
        _Pragma("unroll") for (int mf = 0; mf < 4; ++mf)                      \
            _Pragma("unroll") for (int nf = 0; nf < 4; ++nf)                  \
                MM16(Ar[mf][kk], Br[nf][kk], acc[mf][nf]);                    \
  } while (0)

  // prologue: stage tile 0 into buf 0, drain, barrier.
  STAGE(0, 0);
  VMW(0);
  BAR();

  for (int i = 0; i < NT; ++i) {
    const int d = i & 1;
    STAGE(i + 1, d ^ 1);  // issue early: full phase of latency cover
    READ_FRAGS(d);
    PRIO(1);
    MFMA_ALL();
    PRIO(0);
    VMW(0);  // queue holds exactly tile i+1's 8 loads
    BAR();
  }

  // Epilogue. D lane mapping: col = lane&15, row = (lane>>4)*4 + r.
#pragma unroll
  for (int n = 0; n < 4; ++n) {
    const int col = colBase + wn * 64 + n * 16 + lr;
    float bvv = 0.f;
    if constexpr (HAS_BIAS) bvv = bias[col];
#pragma unroll
    for (int m = 0; m < 4; ++m) {
      const int row0 = rowBase + wm * 64 + m * 16 + g0 * 4;
      f32x4 v = acc[m][n];
      if constexpr (OUT_MODE == 0) {
        unsigned short* C = (unsigned short*)Cv + sC * bz;
#pragma unroll
        for (int r = 0; r < 4; ++r)
          C[(size_t)(row0 + r) * N + col] = f2bf(v[r] * scale + bvv);
      } else if constexpr (OUT_MODE == 1) {
        unsigned short* C = (unsigned short*)Cv;
        const int b = row0 >> 11, s = row0 & 2047;
        u16x4 pk;
#pragma unroll
        for (int r = 0; r < 4; ++r) pk[r] = f2bf(v[r] * scale + bvv);
        *(u16x4*)&C[((size_t)b * N + col) * 2048 + s] = pk;
      } else {
        float* C = (float*)Cv + sC * bz;
#pragma unroll
        for (int r = 0; r < 4; ++r)
          C[(size_t)(row0 + r) * N + col] = v[r] * scale + bvv;
      }
    }
  }
}

// fp32 -> bf16 (RNE) for one embedding and one weight in a single launch.
__global__ __launch_bounds__(256) void conv_pair(
    const float* __restrict__ e, const float* __restrict__ wt,
    unsigned short* __restrict__ eo, unsigned short* __restrict__ wo,
    int ne8, int nw8) {
  const int tot = ne8 + nw8;
  const int stride = gridDim.x * 256;
  for (int i = blockIdx.x * 256 + threadIdx.x; i < tot; i += stride) {
    const float* src;
    unsigned short* dst;
    int k;
    if (i < ne8) { src = e; dst = eo; k = i; }
    else { src = wt; dst = wo; k = i - ne8; }
    float4 a = ((const float4*)src)[2 * k];
    float4 b = ((const float4*)src)[2 * k + 1];
    unsigned short h[8];
    h[0] = f2bf(a.x); h[1] = f2bf(a.y); h[2] = f2bf(a.z); h[3] = f2bf(a.w);
    h[4] = f2bf(b.x); h[5] = f2bf(b.y); h[6] = f2bf(b.z); h[7] = f2bf(b.w);
    ((uint4*)dst)[k] = *(uint4*)h;
  }
}

// In-place softmax over rows of 2048 bf16 scores. One block (256 thr) per row.
__global__ __launch_bounds__(256) void softmax_inplace(unsigned short* __restrict__ S) {
  const size_t row = blockIdx.x;
  unsigned short* p = S + row * 2048;
  const int t = threadIdx.x;
  const int lane = t & 63, wid = t >> 6;

  uint4 x = ((const uint4*)p)[t];
  unsigned short* hs = (unsigned short*)&x;
  float f[8];
#pragma unroll
  for (int j = 0; j < 8; ++j) f[j] = bf2f(hs[j]);

  float mx = f[0];
#pragma unroll
  for (int j = 1; j < 8; ++j) mx = fmaxf(mx, f[j]);
#pragma unroll
  for (int d = 1; d < 64; d <<= 1) mx = fmaxf(mx, __shfl_xor(mx, d));
  __shared__ float redm[4];
  if (lane == 0) redm[wid] = mx;
  __syncthreads();
  mx = fmaxf(fmaxf(redm[0], redm[1]), fmaxf(redm[2], redm[3]));

  float e[8], s = 0.f;
#pragma unroll
  for (int j = 0; j < 8; ++j) {
    e[j] = __expf(f[j] - mx);
    s += e[j];
  }
#pragma unroll
  for (int d = 1; d < 64; d <<= 1) s += __shfl_xor(s, d);
  __shared__ float reds[4];
  if (lane == 0) reds[wid] = s;
  __syncthreads();
  s = reds[0] + reds[1] + reds[2] + reds[3];
  const float inv = 1.f / s;

#pragma unroll
  for (int j = 0; j < 8; ++j) hs[j] = f2bf(e[j] * inv);
  ((uint4*)p)[t] = x;
}

extern "C" void kernel_launch(void* const* d_in, const int* in_sizes, int n_in,
                              void* d_out, int out_size, void* d_ws, size_t ws_size,
                              hipStream_t stream) {
  const float* q_embd = (const float*)d_in[0];
  const float* k_embd = (const float*)d_in[1];
  const float* v_embd = (const float*)d_in[2];
  const float* Wq = (const float*)d_in[3];
  const float* bq = (const float*)d_in[4];
  const float* Wk = (const float*)d_in[5];
  const float* bk = (const float*)d_in[6];
  const float* Wv = (const float*)d_in[7];
  const float* bv = (const float*)d_in[8];

  constexpr int B = 8, QL = 2048, KL = 2048, D = 1024;
  constexpr size_t NE = (size_t)B * QL * D;

  unsigned short* qb = (unsigned short*)d_ws;  // [B*QL][D]
  unsigned short* kb = qb + NE;                // [B*KL][D]
  unsigned short* vT = kb + NE;                // [B][D][KL]
  unsigned short* Sb = vT + NE;                // [B][QL][KL] (64 MiB)
  unsigned short* Xe = Sb;                     // conv staging (dead until QK^T)
  unsigned short* Wb = Sb + NE;

  dim3 blk256(256);
  const dim3 gconv(2048);
  // proj grid: gx = D/128 = 8, gy = (B*QL)/128 = 128 -> 1024 blocks (2/CU)
  const dim3 gproj(8 * 128);
  constexpr int NE8 = (int)(NE / 8), NW8 = D * D / 8;

  // --- Q projection ---
  conv_pair<<<gconv, blk256, 0, stream>>>(q_embd, Wq, Xe, Wb, NE8, NW8);
  gemm128<0, true><<<gproj, blk256, 0, stream>>>(Xe, Wb, bq, 1.0f, qb, D, D,
                                                 0L, 0L, 0L, 8, 128);
  // --- K projection ---
  conv_pair<<<gconv, blk256, 0, stream>>>(k_embd, Wk, Xe, Wb, NE8, NW8);
  gemm128<0, true><<<gproj, blk256, 0, stream>>>(Xe, Wb, bk, 1.0f, kb, D, D,
                                                 0L, 0L, 0L, 8, 128);
  // --- V projection (transposed output) ---
  conv_pair<<<gconv, blk256, 0, stream>>>(v_embd, Wv, Xe, Wb, NE8, NW8);
  gemm128<1, true><<<gproj, blk256, 0, stream>>>(Xe, Wb, bv, 1.0f, vT, D, D,
                                                 0L, 0L, 0L, 8, 128);

  // --- S = (Q @ K^T)/sqrt(D): gx=16, gy=16, gz=8 -> 2048 blocks ---
  gemm128<0, false><<<dim3(2048), blk256, 0, stream>>>(
      qb, kb, nullptr, 0.03125f, Sb, KL, D, (long)QL * D, (long)KL * D,
      (long)QL * KL, 16, 16);

  // --- P = softmax(S), in place ---
  softmax_inplace<<<dim3(B * QL), blk256, 0, stream>>>(Sb);

  // --- out = P @ V: gx=8, gy=16, gz=8 -> 1024 blocks ---
  gemm128<2, false><<<dim3(1024), blk256, 0, stream>>>(
      Sb, vT, nullptr, 1.0f, d_out, D, KL, (long)QL * KL, (long)D * KL,
      (long)QL * D, 8, 16);
}